// Round 1
// baseline (115.107 us; speedup 1.0000x reference)
//
#include <hip/hip_runtime.h>

// SyntheticTripletLoss: B=32, T=512, D=512 fp32.
// Analytic collapse: with pt=dot(p,t), pp=dot(p,p), tt=dot(t,t):
//   norm^2 = pp - 2*pt^2 + pt^2*tt
//   sim_pn = (pp - pt^2) / max(norm, EPS)
//   loss   = max(0.5 + sim_pn - pt, 0), masked mean over t < len[b]
//
// R1: same-address atomics serialized (60 us) -> per-block partials.
// R2: grid 1024 -> 16 waves/CU = 52% occupancy, latency-bound.
// R3: 2048 blocks x 4 waves, 2 rows/wave -> 32 waves/CU (100%), 8 independent
//     float4-pair loads per wave; single-wave finalize (float4 partial reads).
// R4: rocprof shows dur_us is dominated by two 256 MiB workspace-poison fills
//     (~84 us) in the timed window; kernels themselves are ~8 us (inputs are
//     L3-resident, FETCH_SIZE ~0). Go workspace-free: per-block partial ->
//     one pre-scaled atomicAdd into d_out; tiny zeroing kernel replaces the
//     finalize pass. Tests whether the ws poison leaves the timed path.

#define MARGIN 0.5f
#define EPS_N 1e-12f

static constexpr int BB     = 32;
static constexpr int TT_DIM = 512;
static constexpr int DD     = 512;
static constexpr int GRID1  = 2048;   // blocks in main kernel
static constexpr int ROWS_PER_WAVE = 2;

// out is poisoned by the harness each iteration; zero it (stream-ordered
// before the atomics in the main kernel).
__global__ __launch_bounds__(64) void triplet_zero(float* __restrict__ out)
{
    if (threadIdx.x == 0) out[0] = 0.f;
}

// 2048 blocks x 4 waves; each wave handles 2 consecutive rows.
// Block partial is scaled by 1/denom and atomicAdd'ed into out[0]
// (device-scope by default, correct across XCDs). No workspace use.
__global__ __launch_bounds__(256) void triplet_rows_atomic(
    const float* __restrict__ preds,
    const float* __restrict__ targets,
    const int* __restrict__ lengths,
    float* __restrict__ out)
{
    const int wave  = threadIdx.x >> 6;
    const int lane  = threadIdx.x & 63;
    const int wglob = blockIdx.x * 4 + wave;            // [0, 8192)
    const int row0  = wglob * ROWS_PER_WAVE;

    float wacc = 0.f;

    #pragma unroll
    for (int r = 0; r < ROWS_PER_WAVE; ++r) {
        const int row = row0 + r;
        const int b   = row >> 9;                       // row / T
        const int t   = row & (TT_DIM - 1);             // row % T

        const float4* p4 = reinterpret_cast<const float4*>(preds   + (size_t)row * DD);
        const float4* t4 = reinterpret_cast<const float4*>(targets + (size_t)row * DD);

        // issue all 4 loads for this row up front (independent)
        float4 pa = p4[lane];
        float4 qa = t4[lane];
        float4 pb = p4[lane + 64];
        float4 qb = t4[lane + 64];

        float pp = pa.x * pa.x + pa.y * pa.y + pa.z * pa.z + pa.w * pa.w
                 + pb.x * pb.x + pb.y * pb.y + pb.z * pb.z + pb.w * pb.w;
        float pt = pa.x * qa.x + pa.y * qa.y + pa.z * qa.z + pa.w * qa.w
                 + pb.x * qb.x + pb.y * qb.y + pb.z * qb.z + pb.w * qb.w;
        float tt = qa.x * qa.x + qa.y * qa.y + qa.z * qa.z + qa.w * qa.w
                 + qb.x * qb.x + qb.y * qb.y + qb.z * qb.z + qb.w * qb.w;

        // butterfly: all 64 lanes end with the full row sums
        #pragma unroll
        for (int m = 32; m > 0; m >>= 1) {
            pp += __shfl_xor(pp, m, 64);
            pt += __shfl_xor(pt, m, 64);
            tt += __shfl_xor(tt, m, 64);
        }

        // uniform per-row epilogue (all lanes identical)
        float pt2 = pt * pt;
        float n2  = pp - 2.f * pt2 + pt2 * tt;
        float nrm = sqrtf(fmaxf(n2, 0.f));
        float spn = (pp - pt2) / fmaxf(nrm, EPS_N);
        float l   = fmaxf(MARGIN + spn - pt, 0.f);
        if (t < lengths[b]) wacc += l;
    }

    __shared__ float wsum[4];
    if (lane == 0) wsum[wave] = wacc;
    __syncthreads();

    if (threadIdx.x == 0) {
        float bsum = wsum[0] + wsum[1] + wsum[2] + wsum[3];
        // denom = sum(lengths): 32 L1/L2-hit loads per block, negligible
        int denom = 0;
        #pragma unroll
        for (int bb = 0; bb < BB; ++bb) denom += lengths[bb];
        atomicAdd(out, bsum / (float)denom);
    }
}

extern "C" void kernel_launch(void* const* d_in, const int* in_sizes, int n_in,
                              void* d_out, int out_size, void* d_ws, size_t ws_size,
                              hipStream_t stream)
{
    const float* preds   = (const float*)d_in[0];
    const float* targets = (const float*)d_in[1];
    const int*   lengths = (const int*)d_in[2];
    float* out = (float*)d_out;
    (void)d_ws; (void)ws_size;   // workspace deliberately untouched (R4)

    triplet_zero<<<1, 64, 0, stream>>>(out);
    triplet_rows_atomic<<<GRID1, 256, 0, stream>>>(preds, targets, lengths, out);
}

// Round 2
// 92.308 us; speedup vs baseline: 1.2470x; 1.2470x over previous
//
#include <hip/hip_runtime.h>

// SyntheticTripletLoss: B=32, T=512, D=512 fp32.
// Analytic collapse: with pt=dot(p,t), pp=dot(p,p), tt=dot(t,t):
//   norm^2 = pp - 2*pt^2 + pt^2*tt
//   sim_pn = (pp - pt^2) / max(norm, EPS)
//   loss   = max(0.5 + sim_pn - pt, 0), masked mean over t < len[b]
//
// R1: same-address atomics serialized (60 us) -> per-block partials.
// R2: grid 1024 -> 16 waves/CU = 52% occupancy, latency-bound.
// R3: 2048 blocks x 4 waves, 2 rows/wave -> 32 waves/CU (100%), 8 independent
//     float4-pair loads per wave; single-wave finalize (float4 partial reads).
// R4: FAILED (115 us). Went workspace-free + single-address atomics to test
//     whether the 2x256MiB ws-poison fills (~84 us) leave the timed window.
//     They do NOT - poison is unconditional. Atomic tail added ~15 us and the
//     extra zero-dispatch ~5 us. Lesson: ws use is free; atomics are not.
// R5: revert to R3 structure. Finalize tweak: lengths[] loaded in parallel
//     across lanes 0..31 BEFORE the partial reads (overlap L2 latency),
//     denominator reduced in the same butterfly.
//
// Structural floor: 84 us unconditional poison + ~6 us L3-BW-bound main
// kernel (67 MB resident reads) + ~1.5 us finalize ≈ 91 us.

#define MARGIN 0.5f
#define EPS_N 1e-12f

static constexpr int BB     = 32;
static constexpr int TT_DIM = 512;
static constexpr int DD     = 512;
static constexpr int GRID1  = 2048;   // blocks in stage 1
static constexpr int ROWS_PER_WAVE = 2;

// 2048 blocks x 4 waves; each wave handles 2 consecutive rows.
__global__ __launch_bounds__(256) void triplet_rows(
    const float* __restrict__ preds,
    const float* __restrict__ targets,
    const int* __restrict__ lengths,
    float* __restrict__ ws_partial)
{
    const int wave  = threadIdx.x >> 6;
    const int lane  = threadIdx.x & 63;
    const int wglob = blockIdx.x * 4 + wave;            // [0, 8192)
    const int row0  = wglob * ROWS_PER_WAVE;

    float wacc = 0.f;

    #pragma unroll
    for (int r = 0; r < ROWS_PER_WAVE; ++r) {
        const int row = row0 + r;
        const int b   = row >> 9;                       // row / T
        const int t   = row & (TT_DIM - 1);             // row % T

        const float4* p4 = reinterpret_cast<const float4*>(preds   + (size_t)row * DD);
        const float4* t4 = reinterpret_cast<const float4*>(targets + (size_t)row * DD);

        // issue all 4 loads for this row up front (independent)
        float4 pa = p4[lane];
        float4 qa = t4[lane];
        float4 pb = p4[lane + 64];
        float4 qb = t4[lane + 64];

        float pp = pa.x * pa.x + pa.y * pa.y + pa.z * pa.z + pa.w * pa.w
                 + pb.x * pb.x + pb.y * pb.y + pb.z * pb.z + pb.w * pb.w;
        float pt = pa.x * qa.x + pa.y * qa.y + pa.z * qa.z + pa.w * qa.w
                 + pb.x * qb.x + pb.y * qb.y + pb.z * qb.z + pb.w * qb.w;
        float tt = qa.x * qa.x + qa.y * qa.y + qa.z * qa.z + qa.w * qa.w
                 + qb.x * qb.x + qb.y * qb.y + qb.z * qb.z + qb.w * qb.w;

        // butterfly: all 64 lanes end with the full row sums
        #pragma unroll
        for (int m = 32; m > 0; m >>= 1) {
            pp += __shfl_xor(pp, m, 64);
            pt += __shfl_xor(pt, m, 64);
            tt += __shfl_xor(tt, m, 64);
        }

        // uniform per-row epilogue (all lanes identical)
        float pt2 = pt * pt;
        float n2  = pp - 2.f * pt2 + pt2 * tt;
        float nrm = sqrtf(fmaxf(n2, 0.f));
        float spn = (pp - pt2) / fmaxf(nrm, EPS_N);
        float l   = fmaxf(MARGIN + spn - pt, 0.f);
        if (t < lengths[b]) wacc += l;
    }

    __shared__ float wsum[4];
    if (lane == 0) wsum[wave] = wacc;
    __syncthreads();
    if (threadIdx.x == 0)
        ws_partial[blockIdx.x] = wsum[0] + wsum[1] + wsum[2] + wsum[3];
}

// single wave: reduce 2048 partials (8 float4 per lane), divide by sum(lengths).
// lengths issued first (lanes 0..31) so the L2 latency overlaps the partial reads.
__global__ __launch_bounds__(64) void triplet_finalize(
    const float* __restrict__ ws_partial,
    const int* __restrict__ lengths,
    float* __restrict__ out)
{
    const int lane = threadIdx.x & 63;

    // parallel denominator load (lanes 0..31), issued before partial reads
    int den = (lane < BB) ? lengths[lane] : 0;

    const float4* p4 = reinterpret_cast<const float4*>(ws_partial);
    float s = 0.f;
    #pragma unroll
    for (int i = 0; i < 8; ++i) {
        float4 v = p4[lane + 64 * i];   // 64 lanes * 8 * 4 = 2048 floats
        s += v.x + v.y + v.z + v.w;
    }

    #pragma unroll
    for (int m = 32; m > 0; m >>= 1) {
        s   += __shfl_xor(s, m, 64);
        den += __shfl_xor(den, m, 64);
    }

    if (lane == 0) out[0] = s / (float)den;
}

extern "C" void kernel_launch(void* const* d_in, const int* in_sizes, int n_in,
                              void* d_out, int out_size, void* d_ws, size_t ws_size,
                              hipStream_t stream)
{
    const float* preds   = (const float*)d_in[0];
    const float* targets = (const float*)d_in[1];
    const int*   lengths = (const int*)d_in[2];
    float* out  = (float*)d_out;
    float* part = (float*)d_ws;   // GRID1 floats, fully overwritten each launch

    triplet_rows<<<GRID1, 256, 0, stream>>>(preds, targets, lengths, part);
    triplet_finalize<<<1, 64, 0, stream>>>(part, lengths, out);
}